// Round 12
// baseline (362.490 us; speedup 1.0000x reference)
//
#include <hip/hip_runtime.h>
#include <hip/hip_bf16.h>
#include <hip/hip_fp16.h>

#define N_NODES 100000
#define N_EDGES 3200000
#define F_IN    128
#define F_H     64

#define NBUCK 512
#define NPB   196            // ceil(N_NODES / NBUCK); max bucket index 510
#define SRC_BITS 17          // N_NODES < 2^17; pack = (dstLocal<<17)|src (25 bits)

// ---------------------------------------------------------------------------
// Bucket-level histogram: 512 bins, LDS-aggregated
// ---------------------------------------------------------------------------
#define BH_T 256
#define BH_C 8192            // edges per block -> 391 blocks
__global__ __launch_bounds__(BH_T) void k_bhist(const int* __restrict__ dst,
                                                int* __restrict__ bcount) {
    __shared__ int lc[NBUCK];
    int t = threadIdx.x;
    lc[t] = 0; lc[t + 256] = 0;
    __syncthreads();
    long long e0 = (long long)blockIdx.x * BH_C;
    long long e1 = e0 + BH_C; if (e1 > N_EDGES) e1 = N_EDGES;
    for (long long e = e0 + t; e < e1; e += BH_T)
        atomicAdd(&lc[dst[e] / NPB], 1);
    __syncthreads();
    int c0 = lc[t], c1 = lc[t + 256];
    if (c0) atomicAdd(&bcount[t], c0);
    if (c1) atomicAdd(&bcount[t + 256], c1);
}

// ---------------------------------------------------------------------------
// Scan of 512 bucket counts -> bucket bases + partA cursors; row_ptr[N]=E
// ---------------------------------------------------------------------------
__global__ __launch_bounds__(NBUCK) void k_bscan(const int* __restrict__ bcount,
                                                 int* __restrict__ bbase,
                                                 int* __restrict__ bcur,
                                                 int* __restrict__ row_ptr) {
    __shared__ int s[NBUCK];
    int t = threadIdx.x;
    int c = bcount[t];
    s[t] = c;
    __syncthreads();
    for (int off = 1; off < NBUCK; off <<= 1) {
        int v = (t >= off) ? s[t - off] : 0;
        __syncthreads();
        s[t] += v;
        __syncthreads();
    }
    int ex = s[t] - c;
    bbase[t] = ex;
    bcur[t]  = ex;
    if (t == NBUCK - 1) {
        bbase[NBUCK] = s[t];             // = N_EDGES
        row_ptr[N_NODES] = s[t];
    }
}

// ---------------------------------------------------------------------------
// wc2 = W2^T Wc (64-vector), c0 = Wc.b2 + bc  — collapses layer2+head
// ---------------------------------------------------------------------------
__global__ __launch_bounds__(64) void k_wc2(const float* __restrict__ W2,
                                            const float* __restrict__ Wc,
                                            const float* __restrict__ b2,
                                            const float* __restrict__ bc,
                                            float* __restrict__ wc2,
                                            float* __restrict__ c0) {
    int k = threadIdx.x;
    float s = 0.0f;
#pragma unroll 8
    for (int f = 0; f < F_H; f++) s += Wc[f] * W2[f * F_H + k];
    wc2[k] = s;
    float p = Wc[k] * b2[k];
#pragma unroll
    for (int off = 32; off > 0; off >>= 1) p += __shfl_xor(p, off, 64);
    if (k == 0) c0[0] = p + bc[0];
}

// ---------------------------------------------------------------------------
// Pass A: partition edges into 512 dst-range buckets; emit packed
// (dstLocal<<17)|src words (LDS-staged, coalesced out). 4K edges/block.
// ---------------------------------------------------------------------------
#define PA_T   256
#define PA_C   4096
#define PA_PER (PA_C / PA_T)   // 16
__global__ __launch_bounds__(PA_T) void k_partA(const int* __restrict__ src,
                                                const int* __restrict__ dst,
                                                int* __restrict__ bucket_cursor,
                                                int* __restrict__ packT) {
    __shared__ int lcount[NBUCK];
    __shared__ int lstart[NBUCK];
    __shared__ int loffs[NBUCK];
    __shared__ int lbase[NBUCK];
    __shared__ int s_pack[PA_C];
    __shared__ short s_bkt[PA_C];
    __shared__ int ltot;
    int t = threadIdx.x;
    long long e0 = (long long)blockIdx.x * PA_C;
    lcount[t] = 0; lcount[t + 256] = 0;
    __syncthreads();
    int ep[PA_PER];
    short eb[PA_PER];
#pragma unroll
    for (int i = 0; i < PA_PER; i++) {
        long long e = e0 + i * PA_T + t;
        if (e < N_EDGES) {
            int es = src[e], ed = dst[e];
            int b = ed / NPB;
            eb[i] = (short)b;
            ep[i] = ((ed - b * NPB) << SRC_BITS) | es;
            atomicAdd(&lcount[b], 1);
        } else eb[i] = -1;
    }
    __syncthreads();
    // exclusive scan of lcount (512) by wave 0: 8 serial/lane + shfl scan
    if (t < 64) {
        int base = t * 8;
        int c[8]; int ssum = 0;
#pragma unroll
        for (int j = 0; j < 8; j++) { c[j] = lcount[base + j]; ssum += c[j]; }
        int sc = ssum;
#pragma unroll
        for (int off = 1; off < 64; off <<= 1) {
            int v = __shfl_up(sc, off, 64);
            if (t >= off) sc += v;
        }
        int ex = sc - ssum;
#pragma unroll
        for (int j = 0; j < 8; j++) { lstart[base + j] = ex; ex += c[j]; }
        if (t == 63) ltot = ex;
    }
    __syncthreads();
    {
        int b0 = t, b1 = t + 256;
        loffs[b0] = lstart[b0];
        loffs[b1] = lstart[b1];
        int c0 = lcount[b0], c1 = lcount[b1];
        lbase[b0] = c0 ? atomicAdd(&bucket_cursor[b0], c0) : 0;
        lbase[b1] = c1 ? atomicAdd(&bucket_cursor[b1], c1) : 0;
    }
    __syncthreads();
#pragma unroll
    for (int i = 0; i < PA_PER; i++) {
        if (eb[i] >= 0) {
            int idx = atomicAdd(&loffs[eb[i]], 1);
            s_pack[idx] = ep[i];
            s_bkt[idx] = eb[i];
        }
    }
    __syncthreads();
    int tot = ltot;
    for (int i = t; i < tot; i += PA_T) {
        int b = s_bkt[i];
        int addr = lbase[b] + (i - lstart[b]);
        packT[addr] = s_pack[i];
    }
}

// ---------------------------------------------------------------------------
// Pass B: per-bucket LDS counting sort of packed words -> srcs[] segment,
// plus derives row_ptr[node] and dinv[node] from the local histogram.
// 512 blocks, ~34 KB LDS -> 4 blocks/CU.
// ---------------------------------------------------------------------------
#define PB_T   512
#define PB_CAP 8192
__global__ __launch_bounds__(PB_T) void k_partB(const int* __restrict__ bbase,
                                                const int* __restrict__ packT,
                                                int* __restrict__ row_ptr,
                                                float* __restrict__ dinv,
                                                int* __restrict__ srcs) {
    __shared__ int lhist[NPB];
    __shared__ int lcur[NPB];
    __shared__ int s_out[PB_CAP];
    int b = blockIdx.x;
    int node0 = b * NPB;
    int nloc = N_NODES - node0; if (nloc > NPB) nloc = NPB; if (nloc < 0) nloc = 0;
    int beg = bbase[b];
    int end = bbase[b + 1];
    int len = end - beg;
    int t = threadIdx.x;
    const int SMASK = (1 << SRC_BITS) - 1;

    for (int i = t; i < NPB; i += PB_T) lhist[i] = 0;
    __syncthreads();
    for (int i = t; i < len; i += PB_T)
        atomicAdd(&lhist[packT[beg + i] >> SRC_BITS], 1);
    __syncthreads();
    if (t < 64) {   // exclusive scan of 196 counters: 4/lane + shfl
        int base = t * 4;
        int c[4]; int ssum = 0;
#pragma unroll
        for (int j = 0; j < 4; j++) {
            int idx = base + j;
            c[j] = (idx < NPB) ? lhist[idx] : 0;
            ssum += c[j];
        }
        int sc = ssum;
#pragma unroll
        for (int off = 1; off < 64; off <<= 1) {
            int v = __shfl_up(sc, off, 64);
            if (t >= off) sc += v;
        }
        int ex = sc - ssum;
#pragma unroll
        for (int j = 0; j < 4; j++) {
            int idx = base + j;
            if (idx < NPB) lcur[idx] = ex;
            ex += c[j];
        }
    }
    __syncthreads();
    // derive row_ptr / dinv from local exclusive prefix (before lcur mutates)
    for (int i = t; i < nloc; i += PB_T) {
        row_ptr[node0 + i] = beg + lcur[i];
        dinv[node0 + i] = rsqrtf((float)(lhist[i] + 1));
    }
    __syncthreads();
    if (len <= PB_CAP) {
        for (int i = t; i < len; i += PB_T) {
            int pk = packT[beg + i];
            int idx = atomicAdd(&lcur[pk >> SRC_BITS], 1);
            s_out[idx] = pk & SMASK;
        }
        __syncthreads();
        for (int i = t; i < len; i += PB_T)
            srcs[beg + i] = s_out[i];
    } else {    // statistically never: direct global scatter
        for (int i = t; i < len; i += PB_T) {
            int pk = packT[beg + i];
            int idx = atomicAdd(&lcur[pk >> SRC_BITS], 1);
            srcs[beg + idx] = pk & SMASK;
        }
    }
}

// ---------------------------------------------------------------------------
// Layer-1 GEMM: hq[quarter][node][16f] = fp16( (x @ W1^T) * dinv )
// NTB=64 -> 1564 blocks (~6/CU available), 33.8 KB LDS -> 4 blocks/CU
// resident = 16 waves/CU with staggered barriers across 2 rounds.
// Wave tile 64f x 16n; lane(fi 0..15, ni 0..3) owns 4f x 4n accumulator.
// ---------------------------------------------------------------------------
#define GT   256
#define NTB  64      // nodes per block
#define KT   64      // k-tile (2 passes for F_IN=128)
#define WTS  68      // wT stride (words)
#define QSTRIDE ((size_t)(N_NODES + 1) * 8)   // __half2 per quarter

__global__ __launch_bounds__(GT) void k_gemm1(const float* __restrict__ x,
                                              const float* __restrict__ W1,
                                              const float* __restrict__ dinv,
                                              __half2* __restrict__ hq) {
    __shared__ float wT[KT * WTS];     // 17.4 KB
    __shared__ float xT[KT * NTB];     // 16 KB
    int t = threadIdx.x;
    int node0 = blockIdx.x * NTB;
    int lane = t & 63, wv = t >> 6;
    int fi = lane & 15, ni = lane >> 4;
    int n0 = wv * 16 + ni * 4;         // this lane's first node offset in block

    float acc[4][4];
#pragma unroll
    for (int r = 0; r < 4; r++)
#pragma unroll
        for (int c = 0; c < 4; c++) acc[r][c] = 0.0f;

    for (int p = 0; p < 2; p++) {
        int k0 = p * KT;
        if (p) __syncthreads();
        // stage W1 chunk (transposed): 64f x 64k, thread (f=t&63, kq=t>>6)
        {
            int f = t & 63, kq = t >> 6;
            const float4* wp = (const float4*)&W1[(size_t)f * F_IN + k0 + kq * 16];
#pragma unroll
            for (int j = 0; j < 4; j++) {
                float4 v = wp[j];
                int kl = kq * 16 + 4 * j;
                wT[(kl + 0) * WTS + f] = v.x;
                wT[(kl + 1) * WTS + f] = v.y;
                wT[(kl + 2) * WTS + f] = v.z;
                wT[(kl + 3) * WTS + f] = v.w;
            }
        }
        // stage x chunk (transposed): 64n x 64k, thread (n=t&63, kq=t>>6)
        {
            int n = t & 63, kq = t >> 6;
            int node = node0 + n;
#pragma unroll
            for (int j = 0; j < 4; j++) {
                int ku = kq * 4 + j;                   // 0..15
                float4 v = make_float4(0.f, 0.f, 0.f, 0.f);
                if (node < N_NODES)
                    v = *(const float4*)&x[(size_t)node * F_IN + k0 + 4 * ku];
                int kl = 4 * ku;
                xT[(kl + 0) * NTB + n] = v.x;
                xT[(kl + 1) * NTB + n] = v.y;
                xT[(kl + 2) * NTB + n] = v.z;
                xT[(kl + 3) * NTB + n] = v.w;
            }
        }
        __syncthreads();
#pragma unroll 8
        for (int k = 0; k < KT; k++) {
            float4 wf = *(const float4*)&wT[k * WTS + fi * 4];
            float4 xa = *(const float4*)&xT[k * NTB + n0];
            float wr[4] = {wf.x, wf.y, wf.z, wf.w};
            float xv[4] = {xa.x, xa.y, xa.z, xa.w};
#pragma unroll
            for (int r = 0; r < 4; r++)
#pragma unroll
                for (int c = 0; c < 4; c++) acc[r][c] += wr[r] * xv[c];
        }
    }
    // epilogue: features 4fi..4fi+3 -> quarter fi>>2, __half2 offset 2*(fi&3)
#pragma unroll
    for (int c = 0; c < 4; c++) {
        int node = node0 + n0 + c;
        if (node <= N_NODES) {     // node==N_NODES -> zero sentinel row (dv=0)
            float dv = (node < N_NODES) ? dinv[node] : 0.0f;
            __half2 h0 = __floats2half2_rn(acc[0][c] * dv, acc[1][c] * dv);
            __half2 h1 = __floats2half2_rn(acc[2][c] * dv, acc[3][c] * dv);
            __half2* p = hq + (size_t)(fi >> 2) * QSTRIDE + (size_t)node * 8 + 2 * (fi & 3);
            p[0] = h0; p[1] = h1;
        }
    }
}

// ---------------------------------------------------------------------------
// Aggregation pass over one feature-quarter (3.2 MB, L2-resident):
// one wave per node; lane = (r,d): edge-slot r=lane>>3, __half2 d=lane&7.
// Main loop: 64-edge chunks, 8 gathers in flight. Tail: ONE masked chunk,
// out-of-range slots -> zero-sentinel row. No serial remainder.
// ---------------------------------------------------------------------------
__global__ void k_aggq(const int* __restrict__ row_ptr, const int* __restrict__ srcs,
                       const __half2* __restrict__ hq, const float* __restrict__ dinv,
                       const float* __restrict__ b1, const float* __restrict__ wc2,
                       float* __restrict__ q, int pass) {
    unsigned tid = blockIdx.x * blockDim.x + threadIdx.x;
    unsigned node = tid >> 6;
    int lane = tid & 63;
    if (node >= N_NODES) return;
    int d = lane & 7, r = lane >> 3;
    const __half2* hp = hq + (size_t)pass * QSTRIDE;

    int beg = row_ptr[node], end = row_ptr[node + 1];
    float2 acc = make_float2(0.0f, 0.0f);
    if (r == 0) {                              // self-loop once per d-group
        float2 s = __half22float2(hp[(size_t)node * 8 + d]);
        acc.x = s.x; acc.y = s.y;
    }
    int j = beg;
    for (; j + 64 <= end; j += 64) {
        int sv = srcs[j + lane];               // 64 edge indices, coalesced
#pragma unroll
        for (int u = 0; u < 8; u++) {
            int sel = __shfl(sv, u * 8 + r, 64);
            float2 v = __half22float2(hp[(size_t)sel * 8 + d]);
            acc.x += v.x; acc.y += v.y;
        }
    }
    if (j < end) {                             // masked chunk: 8 loads in flight
        int idx = j + lane;
        int sv = srcs[(idx < end) ? idx : (end - 1)];
#pragma unroll
        for (int u = 0; u < 8; u++) {
            int pos = j + u * 8 + r;
            int sel = __shfl(sv, u * 8 + r, 64);
            sel = (pos < end) ? sel : N_NODES;     // zero-sentinel row
            float2 v = __half22float2(hp[(size_t)sel * 8 + d]);
            acc.x += v.x; acc.y += v.y;
        }
    }
    // reduce over edge-slots r (lanes with same d)
    acc.x += __shfl_xor(acc.x, 8, 64);  acc.y += __shfl_xor(acc.y, 8, 64);
    acc.x += __shfl_xor(acc.x, 16, 64); acc.y += __shfl_xor(acc.y, 16, 64);
    acc.x += __shfl_xor(acc.x, 32, 64); acc.y += __shfl_xor(acc.y, 32, 64);
    // partial projection for this quarter
    float dv = dinv[node];
    int f0 = pass * 16 + 2 * d;
    float z0 = fmaxf(dv * acc.x + b1[f0], 0.0f);
    float z1 = fmaxf(dv * acc.y + b1[f0 + 1], 0.0f);
    float p = z0 * wc2[f0] + z1 * wc2[f0 + 1];
    p += __shfl_xor(p, 1, 64);
    p += __shfl_xor(p, 2, 64);
    p += __shfl_xor(p, 4, 64);
    if (lane == 0) {
        if (pass == 0)      q[node] = p;
        else if (pass < 3)  q[node] += p;
        else                q[node] = dv * (q[node] + p);   // final: apply dinv
    }
}

// ---------------------------------------------------------------------------
// Final: out[d] = dinv[d] * (q[d] + sum_{s->d} q[s]) + c0
// one thread per node; q (400 KB) is L2-resident
// ---------------------------------------------------------------------------
__global__ void k_final(const int* __restrict__ row_ptr, const int* __restrict__ srcs,
                        const float* __restrict__ q, const float* __restrict__ dinv,
                        const float* __restrict__ c0, float* __restrict__ out) {
    int node = blockIdx.x * blockDim.x + threadIdx.x;
    if (node >= N_NODES) return;
    int beg = row_ptr[node], end = row_ptr[node + 1];
    float acc = q[node];
    int j = beg;
    for (; j + 4 <= end; j += 4) {
        int s0 = srcs[j], s1 = srcs[j + 1], s2 = srcs[j + 2], s3 = srcs[j + 3];
        float a0 = q[s0], a1 = q[s1], a2 = q[s2], a3 = q[s3];
        acc += (a0 + a1) + (a2 + a3);
    }
    for (; j < end; j++) acc += q[srcs[j]];
    out[node] = dinv[node] * acc + c0[0];
}

// ---------------------------------------------------------------------------
extern "C" void kernel_launch(void* const* d_in, const int* in_sizes, int n_in,
                              void* d_out, int out_size, void* d_ws, size_t ws_size,
                              hipStream_t stream) {
    const float* x  = (const float*)d_in[0];
    const int*   ei = (const int*)d_in[1];
    const int*   src = ei;
    const int*   dst = ei + N_EDGES;
    const float* W1 = (const float*)d_in[2];
    const float* b1 = (const float*)d_in[3];
    const float* W2 = (const float*)d_in[4];
    const float* b2 = (const float*)d_in[5];
    const float* Wc = (const float*)d_in[6];
    const float* bc = (const float*)d_in[7];
    float* out = (float*)d_out;

    char* w = (char*)d_ws;
    int*     bcount  = (int*)w;     w += NBUCK * 4;
    int*     bbase   = (int*)w;     w += (NBUCK + 1) * 4;
    int*     bcur    = (int*)w;     w += NBUCK * 4;
    float*   wc2     = (float*)w;   w += 64 * 4;
    float*   c0      = (float*)w;   w += 4 * 4;
    int*     row_ptr = (int*)w;     w += ((size_t)N_NODES + 4) * 4;
    float*   dinv    = (float*)w;   w += (size_t)N_NODES * 4;
    float*   q       = (float*)w;   w += (size_t)N_NODES * 4;
    int*     srcs    = (int*)w;     w += (size_t)N_EDGES * 4;
    __half2* hq      = (__half2*)w; w += 4 * QSTRIDE * 4;          // 12.8 MB (4 quarters)
    int*     packT   = (int*)w;     w += (size_t)N_EDGES * 4;      // sort intermediate

    const int TB = 256;
    const int NB_BH = (int)(((long long)N_EDGES + BH_C - 1) / BH_C);  // 391
    const int NB_PA = (int)(((long long)N_EDGES + PA_C - 1) / PA_C);  // 782
    const int NB_G  = (N_NODES + NTB - 1) / NTB;                      // 1563

    hipMemsetAsync(bcount, 0, NBUCK * 4, stream);
    k_bhist<<<NB_BH, BH_T, 0, stream>>>(dst, bcount);
    k_bscan<<<1, NBUCK, 0, stream>>>(bcount, bbase, bcur, row_ptr);
    k_wc2  <<<1, 64, 0, stream>>>(W2, Wc, b2, bc, wc2, c0);
    k_partA<<<NB_PA, PA_T, 0, stream>>>(src, dst, bcur, packT);
    k_partB<<<NBUCK, PB_T, 0, stream>>>(bbase, packT, row_ptr, dinv, srcs);

    // layer 1: gemm -> hq (4 feature-quarters, fp16)
    k_gemm1<<<NB_G, GT, 0, stream>>>(x, W1, dinv, hq);

    // aggregation: 4 serialized passes, one L2-resident quarter each
    const int NB_AG = (int)(((unsigned)N_NODES * 64 + TB - 1) / TB);
    for (int p = 0; p < 4; p++)
        k_aggq<<<NB_AG, TB, 0, stream>>>(row_ptr, srcs, hq, dinv, b1, wc2, q, p);

    // collapsed layer 2 + head: scalar gather over q
    k_final<<<(N_NODES + TB - 1) / TB, TB, 0, stream>>>(row_ptr, srcs, q, dinv, c0, out);
}

// Round 13
// 347.994 us; speedup vs baseline: 1.0417x; 1.0417x over previous
//
#include <hip/hip_runtime.h>
#include <hip/hip_bf16.h>
#include <hip/hip_fp16.h>

#define N_NODES 100000
#define N_EDGES 3200000
#define F_IN    128
#define F_H     64

#define NBUCK 512
#define NPB   196            // ceil(N_NODES / NBUCK); max bucket index 510
#define SRC_BITS 17          // N_NODES < 2^17; pack = (dstLocal<<17)|src (25 bits)

// ---------------------------------------------------------------------------
// Bucket-level histogram: 512 bins, LDS-aggregated
// ---------------------------------------------------------------------------
#define BH_T 256
#define BH_C 8192            // edges per block -> 391 blocks
__global__ __launch_bounds__(BH_T) void k_bhist(const int* __restrict__ dst,
                                                int* __restrict__ bcount) {
    __shared__ int lc[NBUCK];
    int t = threadIdx.x;
    lc[t] = 0; lc[t + 256] = 0;
    __syncthreads();
    long long e0 = (long long)blockIdx.x * BH_C;
    long long e1 = e0 + BH_C; if (e1 > N_EDGES) e1 = N_EDGES;
    for (long long e = e0 + t; e < e1; e += BH_T)
        atomicAdd(&lc[dst[e] / NPB], 1);
    __syncthreads();
    int c0 = lc[t], c1 = lc[t + 256];
    if (c0) atomicAdd(&bcount[t], c0);
    if (c1) atomicAdd(&bcount[t + 256], c1);
}

// ---------------------------------------------------------------------------
// Scan of 512 bucket counts -> bucket bases + partA cursors; row_ptr[N]=E
// ---------------------------------------------------------------------------
__global__ __launch_bounds__(NBUCK) void k_bscan(const int* __restrict__ bcount,
                                                 int* __restrict__ bbase,
                                                 int* __restrict__ bcur,
                                                 int* __restrict__ row_ptr) {
    __shared__ int s[NBUCK];
    int t = threadIdx.x;
    int c = bcount[t];
    s[t] = c;
    __syncthreads();
    for (int off = 1; off < NBUCK; off <<= 1) {
        int v = (t >= off) ? s[t - off] : 0;
        __syncthreads();
        s[t] += v;
        __syncthreads();
    }
    int ex = s[t] - c;
    bbase[t] = ex;
    bcur[t]  = ex;
    if (t == NBUCK - 1) {
        bbase[NBUCK] = s[t];             // = N_EDGES
        row_ptr[N_NODES] = s[t];
    }
}

// ---------------------------------------------------------------------------
// wc2 = W2^T Wc (64-vector), c0 = Wc.b2 + bc  — collapses layer2+head
// ---------------------------------------------------------------------------
__global__ __launch_bounds__(64) void k_wc2(const float* __restrict__ W2,
                                            const float* __restrict__ Wc,
                                            const float* __restrict__ b2,
                                            const float* __restrict__ bc,
                                            float* __restrict__ wc2,
                                            float* __restrict__ c0) {
    int k = threadIdx.x;
    float s = 0.0f;
#pragma unroll 8
    for (int f = 0; f < F_H; f++) s += Wc[f] * W2[f * F_H + k];
    wc2[k] = s;
    float p = Wc[k] * b2[k];
#pragma unroll
    for (int off = 32; off > 0; off >>= 1) p += __shfl_xor(p, off, 64);
    if (k == 0) c0[0] = p + bc[0];
}

// ---------------------------------------------------------------------------
// Pass A: partition edges into 512 dst-range buckets; emit packed
// (dstLocal<<17)|src words (LDS-staged, coalesced out). 8K edges/block
// -> 16-edge (64 B) bucket runs, one cache line per run.
// ---------------------------------------------------------------------------
#define PA_T   512
#define PA_C   8192
#define PA_PER (PA_C / PA_T)   // 16
__global__ __launch_bounds__(PA_T) void k_partA(const int* __restrict__ src,
                                                const int* __restrict__ dst,
                                                int* __restrict__ bucket_cursor,
                                                int* __restrict__ packT) {
    __shared__ int lcount[NBUCK];
    __shared__ int lstart[NBUCK];
    __shared__ int loffs[NBUCK];
    __shared__ int lbase[NBUCK];
    __shared__ int s_pack[PA_C];    // 32 KB
    __shared__ short s_bkt[PA_C];   // 16 KB
    __shared__ int ltot;
    int t = threadIdx.x;
    long long e0 = (long long)blockIdx.x * PA_C;
    lcount[t] = 0;                  // PA_T == NBUCK
    __syncthreads();
    int ep[PA_PER];
    short eb[PA_PER];
#pragma unroll
    for (int i = 0; i < PA_PER; i++) {
        long long e = e0 + i * PA_T + t;
        if (e < N_EDGES) {
            int es = src[e], ed = dst[e];
            int b = ed / NPB;
            eb[i] = (short)b;
            ep[i] = ((ed - b * NPB) << SRC_BITS) | es;
            atomicAdd(&lcount[b], 1);
        } else eb[i] = -1;
    }
    __syncthreads();
    // exclusive scan of lcount (512) by wave 0: 8 serial/lane + shfl scan
    if (t < 64) {
        int base = t * 8;
        int c[8]; int ssum = 0;
#pragma unroll
        for (int j = 0; j < 8; j++) { c[j] = lcount[base + j]; ssum += c[j]; }
        int sc = ssum;
#pragma unroll
        for (int off = 1; off < 64; off <<= 1) {
            int v = __shfl_up(sc, off, 64);
            if (t >= off) sc += v;
        }
        int ex = sc - ssum;
#pragma unroll
        for (int j = 0; j < 8; j++) { lstart[base + j] = ex; ex += c[j]; }
        if (t == 63) ltot = ex;
    }
    __syncthreads();
    {
        loffs[t] = lstart[t];
        int c = lcount[t];
        lbase[t] = c ? atomicAdd(&bucket_cursor[t], c) : 0;
    }
    __syncthreads();
#pragma unroll
    for (int i = 0; i < PA_PER; i++) {
        if (eb[i] >= 0) {
            int idx = atomicAdd(&loffs[eb[i]], 1);
            s_pack[idx] = ep[i];
            s_bkt[idx] = eb[i];
        }
    }
    __syncthreads();
    int tot = ltot;
    for (int i = t; i < tot; i += PA_T) {
        int b = s_bkt[i];
        int addr = lbase[b] + (i - lstart[b]);
        packT[addr] = s_pack[i];
    }
}

// ---------------------------------------------------------------------------
// Pass B: per-bucket LDS counting sort of packed words -> srcs[] segment,
// plus derives row_ptr[node] and dinv[node] from the local histogram.
// 512 blocks, ~34 KB LDS -> 4 blocks/CU.
// ---------------------------------------------------------------------------
#define PB_T   512
#define PB_CAP 8192
__global__ __launch_bounds__(PB_T) void k_partB(const int* __restrict__ bbase,
                                                const int* __restrict__ packT,
                                                int* __restrict__ row_ptr,
                                                float* __restrict__ dinv,
                                                int* __restrict__ srcs) {
    __shared__ int lhist[NPB];
    __shared__ int lcur[NPB];
    __shared__ int s_out[PB_CAP];
    int b = blockIdx.x;
    int node0 = b * NPB;
    int nloc = N_NODES - node0; if (nloc > NPB) nloc = NPB; if (nloc < 0) nloc = 0;
    int beg = bbase[b];
    int end = bbase[b + 1];
    int len = end - beg;
    int t = threadIdx.x;
    const int SMASK = (1 << SRC_BITS) - 1;

    for (int i = t; i < NPB; i += PB_T) lhist[i] = 0;
    __syncthreads();
    for (int i = t; i < len; i += PB_T)
        atomicAdd(&lhist[packT[beg + i] >> SRC_BITS], 1);
    __syncthreads();
    if (t < 64) {   // exclusive scan of 196 counters: 4/lane + shfl
        int base = t * 4;
        int c[4]; int ssum = 0;
#pragma unroll
        for (int j = 0; j < 4; j++) {
            int idx = base + j;
            c[j] = (idx < NPB) ? lhist[idx] : 0;
            ssum += c[j];
        }
        int sc = ssum;
#pragma unroll
        for (int off = 1; off < 64; off <<= 1) {
            int v = __shfl_up(sc, off, 64);
            if (t >= off) sc += v;
        }
        int ex = sc - ssum;
#pragma unroll
        for (int j = 0; j < 4; j++) {
            int idx = base + j;
            if (idx < NPB) lcur[idx] = ex;
            ex += c[j];
        }
    }
    __syncthreads();
    // derive row_ptr / dinv from local exclusive prefix (before lcur mutates)
    for (int i = t; i < nloc; i += PB_T) {
        row_ptr[node0 + i] = beg + lcur[i];
        dinv[node0 + i] = rsqrtf((float)(lhist[i] + 1));
    }
    __syncthreads();
    if (len <= PB_CAP) {
        for (int i = t; i < len; i += PB_T) {
            int pk = packT[beg + i];
            int idx = atomicAdd(&lcur[pk >> SRC_BITS], 1);
            s_out[idx] = pk & SMASK;
        }
        __syncthreads();
        for (int i = t; i < len; i += PB_T)
            srcs[beg + i] = s_out[i];
    } else {    // statistically never: direct global scatter
        for (int i = t; i < len; i += PB_T) {
            int pk = packT[beg + i];
            int idx = atomicAdd(&lcur[pk >> SRC_BITS], 1);
            srcs[beg + idx] = pk & SMASK;
        }
    }
}

// ---------------------------------------------------------------------------
// Layer-1 GEMM: hq[quarter][node][16f] = fp16( (x @ W1^T) * dinv )
// NTB=64 -> 1564 blocks, 33.8 KB LDS -> 4 blocks/CU resident.
// Wave tile 64f x 16n; lane(fi 0..15, ni 0..3) owns 4f x 4n accumulator.
// ---------------------------------------------------------------------------
#define GT   256
#define NTB  64      // nodes per block
#define KT   64      // k-tile (2 passes for F_IN=128)
#define WTS  68      // wT stride (words)
#define QSTRIDE ((size_t)(N_NODES + 1) * 8)   // __half2 per quarter

__global__ __launch_bounds__(GT) void k_gemm1(const float* __restrict__ x,
                                              const float* __restrict__ W1,
                                              const float* __restrict__ dinv,
                                              __half2* __restrict__ hq) {
    __shared__ float wT[KT * WTS];     // 17.4 KB
    __shared__ float xT[KT * NTB];     // 16 KB
    int t = threadIdx.x;
    int node0 = blockIdx.x * NTB;
    int lane = t & 63, wv = t >> 6;
    int fi = lane & 15, ni = lane >> 4;
    int n0 = wv * 16 + ni * 4;         // this lane's first node offset in block

    float acc[4][4];
#pragma unroll
    for (int r = 0; r < 4; r++)
#pragma unroll
        for (int c = 0; c < 4; c++) acc[r][c] = 0.0f;

    for (int p = 0; p < 2; p++) {
        int k0 = p * KT;
        if (p) __syncthreads();
        // stage W1 chunk (transposed): 64f x 64k, thread (f=t&63, kq=t>>6)
        {
            int f = t & 63, kq = t >> 6;
            const float4* wp = (const float4*)&W1[(size_t)f * F_IN + k0 + kq * 16];
#pragma unroll
            for (int j = 0; j < 4; j++) {
                float4 v = wp[j];
                int kl = kq * 16 + 4 * j;
                wT[(kl + 0) * WTS + f] = v.x;
                wT[(kl + 1) * WTS + f] = v.y;
                wT[(kl + 2) * WTS + f] = v.z;
                wT[(kl + 3) * WTS + f] = v.w;
            }
        }
        // stage x chunk (transposed): 64n x 64k, thread (n=t&63, kq=t>>6)
        {
            int n = t & 63, kq = t >> 6;
            int node = node0 + n;
#pragma unroll
            for (int j = 0; j < 4; j++) {
                int ku = kq * 4 + j;                   // 0..15
                float4 v = make_float4(0.f, 0.f, 0.f, 0.f);
                if (node < N_NODES)
                    v = *(const float4*)&x[(size_t)node * F_IN + k0 + 4 * ku];
                int kl = 4 * ku;
                xT[(kl + 0) * NTB + n] = v.x;
                xT[(kl + 1) * NTB + n] = v.y;
                xT[(kl + 2) * NTB + n] = v.z;
                xT[(kl + 3) * NTB + n] = v.w;
            }
        }
        __syncthreads();
#pragma unroll 8
        for (int k = 0; k < KT; k++) {
            float4 wf = *(const float4*)&wT[k * WTS + fi * 4];
            float4 xa = *(const float4*)&xT[k * NTB + n0];
            float wr[4] = {wf.x, wf.y, wf.z, wf.w};
            float xv[4] = {xa.x, xa.y, xa.z, xa.w};
#pragma unroll
            for (int r = 0; r < 4; r++)
#pragma unroll
                for (int c = 0; c < 4; c++) acc[r][c] += wr[r] * xv[c];
        }
    }
    // epilogue: features 4fi..4fi+3 -> quarter fi>>2, __half2 offset 2*(fi&3)
#pragma unroll
    for (int c = 0; c < 4; c++) {
        int node = node0 + n0 + c;
        if (node <= N_NODES) {     // node==N_NODES -> zero sentinel row (dv=0)
            float dv = (node < N_NODES) ? dinv[node] : 0.0f;
            __half2 h0 = __floats2half2_rn(acc[0][c] * dv, acc[1][c] * dv);
            __half2 h1 = __floats2half2_rn(acc[2][c] * dv, acc[3][c] * dv);
            __half2* p = hq + (size_t)(fi >> 2) * QSTRIDE + (size_t)node * 8 + 2 * (fi & 3);
            p[0] = h0; p[1] = h1;
        }
    }
}

// ---------------------------------------------------------------------------
// Aggregation pass over one feature-quarter (3.2 MB, L2-resident):
// one wave per node; lane = (r,d): edge-slot r=lane>>3, __half2 d=lane&7.
// Main loop: 64-edge chunks, 8 gathers in flight. Tail: ONE masked chunk,
// out-of-range slots -> zero-sentinel row. No serial remainder.
// ---------------------------------------------------------------------------
__global__ void k_aggq(const int* __restrict__ row_ptr, const int* __restrict__ srcs,
                       const __half2* __restrict__ hq, const float* __restrict__ dinv,
                       const float* __restrict__ b1, const float* __restrict__ wc2,
                       float* __restrict__ q, int pass) {
    unsigned tid = blockIdx.x * blockDim.x + threadIdx.x;
    unsigned node = tid >> 6;
    int lane = tid & 63;
    if (node >= N_NODES) return;
    int d = lane & 7, r = lane >> 3;
    const __half2* hp = hq + (size_t)pass * QSTRIDE;

    int beg = row_ptr[node], end = row_ptr[node + 1];
    float2 acc = make_float2(0.0f, 0.0f);
    if (r == 0) {                              // self-loop once per d-group
        float2 s = __half22float2(hp[(size_t)node * 8 + d]);
        acc.x = s.x; acc.y = s.y;
    }
    int j = beg;
    for (; j + 64 <= end; j += 64) {
        int sv = srcs[j + lane];               // 64 edge indices, coalesced
#pragma unroll
        for (int u = 0; u < 8; u++) {
            int sel = __shfl(sv, u * 8 + r, 64);
            float2 v = __half22float2(hp[(size_t)sel * 8 + d]);
            acc.x += v.x; acc.y += v.y;
        }
    }
    if (j < end) {                             // masked chunk: 8 loads in flight
        int idx = j + lane;
        int sv = srcs[(idx < end) ? idx : (end - 1)];
#pragma unroll
        for (int u = 0; u < 8; u++) {
            int pos = j + u * 8 + r;
            int sel = __shfl(sv, u * 8 + r, 64);
            sel = (pos < end) ? sel : N_NODES;     // zero-sentinel row
            float2 v = __half22float2(hp[(size_t)sel * 8 + d]);
            acc.x += v.x; acc.y += v.y;
        }
    }
    // reduce over edge-slots r (lanes with same d)
    acc.x += __shfl_xor(acc.x, 8, 64);  acc.y += __shfl_xor(acc.y, 8, 64);
    acc.x += __shfl_xor(acc.x, 16, 64); acc.y += __shfl_xor(acc.y, 16, 64);
    acc.x += __shfl_xor(acc.x, 32, 64); acc.y += __shfl_xor(acc.y, 32, 64);
    // partial projection for this quarter
    float dv = dinv[node];
    int f0 = pass * 16 + 2 * d;
    float z0 = fmaxf(dv * acc.x + b1[f0], 0.0f);
    float z1 = fmaxf(dv * acc.y + b1[f0 + 1], 0.0f);
    float p = z0 * wc2[f0] + z1 * wc2[f0 + 1];
    p += __shfl_xor(p, 1, 64);
    p += __shfl_xor(p, 2, 64);
    p += __shfl_xor(p, 4, 64);
    if (lane == 0) {
        if (pass == 0)      q[node] = p;
        else if (pass < 3)  q[node] += p;
        else                q[node] = dv * (q[node] + p);   // final: apply dinv
    }
}

// ---------------------------------------------------------------------------
// Final: out[d] = dinv[d] * (q[d] + sum_{s->d} q[s]) + c0
// one thread per node; q (400 KB) is L2-resident
// ---------------------------------------------------------------------------
__global__ void k_final(const int* __restrict__ row_ptr, const int* __restrict__ srcs,
                        const float* __restrict__ q, const float* __restrict__ dinv,
                        const float* __restrict__ c0, float* __restrict__ out) {
    int node = blockIdx.x * blockDim.x + threadIdx.x;
    if (node >= N_NODES) return;
    int beg = row_ptr[node], end = row_ptr[node + 1];
    float acc = q[node];
    int j = beg;
    for (; j + 4 <= end; j += 4) {
        int s0 = srcs[j], s1 = srcs[j + 1], s2 = srcs[j + 2], s3 = srcs[j + 3];
        float a0 = q[s0], a1 = q[s1], a2 = q[s2], a3 = q[s3];
        acc += (a0 + a1) + (a2 + a3);
    }
    for (; j < end; j++) acc += q[srcs[j]];
    out[node] = dinv[node] * acc + c0[0];
}

// ---------------------------------------------------------------------------
extern "C" void kernel_launch(void* const* d_in, const int* in_sizes, int n_in,
                              void* d_out, int out_size, void* d_ws, size_t ws_size,
                              hipStream_t stream) {
    const float* x  = (const float*)d_in[0];
    const int*   ei = (const int*)d_in[1];
    const int*   src = ei;
    const int*   dst = ei + N_EDGES;
    const float* W1 = (const float*)d_in[2];
    const float* b1 = (const float*)d_in[3];
    const float* W2 = (const float*)d_in[4];
    const float* b2 = (const float*)d_in[5];
    const float* Wc = (const float*)d_in[6];
    const float* bc = (const float*)d_in[7];
    float* out = (float*)d_out;

    char* w = (char*)d_ws;
    int*     bcount  = (int*)w;     w += NBUCK * 4;
    int*     bbase   = (int*)w;     w += (NBUCK + 1) * 4;
    int*     bcur    = (int*)w;     w += NBUCK * 4;
    float*   wc2     = (float*)w;   w += 64 * 4;
    float*   c0      = (float*)w;   w += 4 * 4;
    int*     row_ptr = (int*)w;     w += ((size_t)N_NODES + 4) * 4;
    float*   dinv    = (float*)w;   w += (size_t)N_NODES * 4;
    float*   q       = (float*)w;   w += (size_t)N_NODES * 4;
    int*     srcs    = (int*)w;     w += (size_t)N_EDGES * 4;
    __half2* hq      = (__half2*)w; w += 4 * QSTRIDE * 4;          // 12.8 MB (4 quarters)
    int*     packT   = (int*)w;     w += (size_t)N_EDGES * 4;      // sort intermediate

    const int TB = 256;
    const int NB_BH = (int)(((long long)N_EDGES + BH_C - 1) / BH_C);  // 391
    const int NB_PA = (int)(((long long)N_EDGES + PA_C - 1) / PA_C);  // 391
    const int NB_G  = (N_NODES + NTB - 1) / NTB;                      // 1563

    hipMemsetAsync(bcount, 0, NBUCK * 4, stream);
    k_bhist<<<NB_BH, BH_T, 0, stream>>>(dst, bcount);
    k_bscan<<<1, NBUCK, 0, stream>>>(bcount, bbase, bcur, row_ptr);
    k_wc2  <<<1, 64, 0, stream>>>(W2, Wc, b2, bc, wc2, c0);
    k_partA<<<NB_PA, PA_T, 0, stream>>>(src, dst, bcur, packT);
    k_partB<<<NBUCK, PB_T, 0, stream>>>(bbase, packT, row_ptr, dinv, srcs);

    // layer 1: gemm -> hq (4 feature-quarters, fp16)
    k_gemm1<<<NB_G, GT, 0, stream>>>(x, W1, dinv, hq);

    // aggregation: 4 serialized passes, one L2-resident quarter each
    const int NB_AG = (int)(((unsigned)N_NODES * 64 + TB - 1) / TB);
    for (int p = 0; p < 4; p++)
        k_aggq<<<NB_AG, TB, 0, stream>>>(row_ptr, srcs, hq, dinv, b1, wc2, q, p);

    // collapsed layer 2 + head: scalar gather over q
    k_final<<<(N_NODES + TB - 1) / TB, TB, 0, stream>>>(row_ptr, srcs, q, dinv, c0, out);
}